// Round 4
// baseline (156.679 us; speedup 1.0000x reference)
//
#include <hip/hip_runtime.h>
#include <math.h>

#define Tdim 1024
#define Hh   64

// (1/(sqrt(2)*0.8)) * log2(e) — folded into Q so attention uses exp2 directly
__device__ __constant__ float kQScale = 0.8838834764831844f * 1.4426950408889634f;

// ---------------------------------------------------------------------------
// Kernel 1: fused QKV projection, 1 wave per block.
// Wave computes 64 rows x 16 cols of y = x @ W.T.
// grid = (32 row-blocks, 8 col-blocks, 3 matrices), block = 64.
// lane = row; x row lives in 32 float4 VGPRs; W index is wave-uniform
// (blockIdx + loop constants) -> scalar loads.
// Q written (B,T,D) pre-scaled by kQScale (coalesced via LDS transpose);
// K,V written as float2 into packed KV float4 (k0,k1,v0,v1) per (bh,t).
// ---------------------------------------------------------------------------
__global__ __launch_bounds__(64) void qkv_proj(
    const float* __restrict__ x, const float* __restrict__ Wq,
    const float* __restrict__ Wk, const float* __restrict__ Wv,
    float* __restrict__ Q, float* __restrict__ KV)
{
    __shared__ __align__(16) float Ot[64][20];   // 5 KB transpose buffer (Q path)

    const int lane = threadIdx.x;
    const int row  = blockIdx.x * 64 + lane;     // 0..2047
    const int jb   = blockIdx.y * 16;            // col base
    const int mat  = blockIdx.z;                 // 0=Q 1=K 2=V
    const float* W = (mat == 0) ? Wq : (mat == 1) ? Wk : Wv;

    // x row -> registers (32 float4)
    float4 xr[32];
    {
        const float4* xrow = reinterpret_cast<const float4*>(x + (size_t)row * 128);
#pragma unroll
        for (int k = 0; k < 32; ++k) xr[k] = xrow[k];
    }

    for (int cg = 0; cg < 4; ++cg) {             // 4 cols per group
        const float4* w0 = reinterpret_cast<const float4*>(W + (size_t)(jb + cg * 4 + 0) * 128);
        const float4* w1 = reinterpret_cast<const float4*>(W + (size_t)(jb + cg * 4 + 1) * 128);
        const float4* w2 = reinterpret_cast<const float4*>(W + (size_t)(jb + cg * 4 + 2) * 128);
        const float4* w3 = reinterpret_cast<const float4*>(W + (size_t)(jb + cg * 4 + 3) * 128);
        float a0 = 0.f, a1 = 0.f, a2 = 0.f, a3 = 0.f;
#pragma unroll
        for (int k = 0; k < 32; ++k) {
            const float4 xv = xr[k];
            const float4 v0 = w0[k], v1 = w1[k], v2 = w2[k], v3 = w3[k];
            a0 = fmaf(xv.x, v0.x, fmaf(xv.y, v0.y, fmaf(xv.z, v0.z, fmaf(xv.w, v0.w, a0))));
            a1 = fmaf(xv.x, v1.x, fmaf(xv.y, v1.y, fmaf(xv.z, v1.z, fmaf(xv.w, v1.w, a1))));
            a2 = fmaf(xv.x, v2.x, fmaf(xv.y, v2.y, fmaf(xv.z, v2.z, fmaf(xv.w, v2.w, a2))));
            a3 = fmaf(xv.x, v3.x, fmaf(xv.y, v3.y, fmaf(xv.z, v3.z, fmaf(xv.w, v3.w, a3))));
        }
        if (mat == 0) {
            Ot[lane][cg * 4 + 0] = a0 * kQScale;
            Ot[lane][cg * 4 + 1] = a1 * kQScale;
            Ot[lane][cg * 4 + 2] = a2 * kQScale;
            Ot[lane][cg * 4 + 3] = a3 * kQScale;
        } else {
            const int tl = row & 1023, b = row >> 10;
            const int h0 = (jb + cg * 4) >> 1;          // 2 heads per group
            const int off = (mat == 1) ? 0 : 2;
            float* base = KV + (((size_t)(b * Hh + h0) * Tdim + tl) * 4 + off);
            *reinterpret_cast<float2*>(base)        = make_float2(a0, a1);
            *reinterpret_cast<float2*>(base + 4096) = make_float2(a2, a3);  // head h0+1
        }
    }

    if (mat == 0) {
        __syncthreads();   // single wave: cheap lgkmcnt drain + barrier
#pragma unroll
        for (int rep = 0; rep < 4; ++rep) {
            const int r = rep * 16 + (lane >> 2), c4 = lane & 3;
            const float4 v = *reinterpret_cast<const float4*>(&Ot[r][c4 * 4]);
            *reinterpret_cast<float4*>(Q + (size_t)(blockIdx.x * 64 + r) * 128 + jb + c4 * 4) = v;
        }
    }
}

// ---------------------------------------------------------------------------
// Kernel 2: causal attention, head_dim=2, single-pass no-max softmax (exp2
// domain; |score*log2e| small enough that fp32 cannot overflow).
// grid = (8 query-chunks of 128, B*H=128), block = 256.
// Thread owns 4 consecutive queries, 8 sub-lanes stride the keys:
// one ds_read_b128 (8-way broadcast across the wave) feeds 4 query updates.
// Heavy chunks dispatched first (chunk = 7 - bx).
// ---------------------------------------------------------------------------
__global__ __launch_bounds__(256) void attn(
    const float* __restrict__ Q, const float4* __restrict__ KV,
    float* __restrict__ O)
{
    __shared__ float4 KVs[Tdim];   // 16 KB
    const int tid   = threadIdx.x;
    const int chunk = 7 - blockIdx.x;
    const int bh    = blockIdx.y;
    const int nk    = chunk * 128 + 128;

    const float4* KVg = KV + (size_t)bh * Tdim;
    for (int i = tid; i < nk; i += 256) KVs[i] = KVg[i];
    __syncthreads();

    const int g   = tid >> 3;              // 32 groups of 4 queries
    const int sub = tid & 7;               // 8 key sub-lanes
    const int q0  = chunk * 128 + g * 4;   // first query of this thread
    const int b   = bh >> 6, h = bh & 63;

    float2 q[4];
    {
        const float* Qp = Q + (size_t)(b * Tdim + q0) * 128 + h * 2;
#pragma unroll
        for (int i = 0; i < 4; ++i)
            q[i] = *reinterpret_cast<const float2*>(Qp + (size_t)i * 128);
    }

    float l[4]  = {0.f, 0.f, 0.f, 0.f};
    float a0[4] = {0.f, 0.f, 0.f, 0.f};
    float a1[4] = {0.f, 0.f, 0.f, 0.f};

    // main loop: keys 0 .. q0-1 (no predication needed)
#pragma unroll 2
    for (int k = sub; k < q0; k += 8) {
        const float4 kv = KVs[k];
#pragma unroll
        for (int i = 0; i < 4; ++i) {
            const float p = exp2f(fmaf(q[i].x, kv.x, q[i].y * kv.y));
            l[i] += p;
            a0[i] = fmaf(p, kv.z, a0[i]);
            a1[i] = fmaf(p, kv.w, a1[i]);
        }
    }
    // tail: keys q0 .. q0+3, query i sees key q0+sub iff sub <= i
    if (sub < 4) {
        const float4 kv = KVs[q0 + sub];
#pragma unroll
        for (int i = 0; i < 4; ++i) {
            if (sub <= i) {
                const float p = exp2f(fmaf(q[i].x, kv.x, q[i].y * kv.y));
                l[i] += p;
                a0[i] = fmaf(p, kv.z, a0[i]);
                a1[i] = fmaf(p, kv.w, a1[i]);
            }
        }
    }

    // reduce across the 8 sub-lanes
#pragma unroll
    for (int i = 0; i < 4; ++i) {
        l[i]  += __shfl_xor(l[i], 1);  l[i]  += __shfl_xor(l[i], 2);  l[i]  += __shfl_xor(l[i], 4);
        a0[i] += __shfl_xor(a0[i], 1); a0[i] += __shfl_xor(a0[i], 2); a0[i] += __shfl_xor(a0[i], 4);
        a1[i] += __shfl_xor(a1[i], 1); a1[i] += __shfl_xor(a1[i], 2); a1[i] += __shfl_xor(a1[i], 4);
    }

    if (sub == 0) {
        float* Op = O + (size_t)(b * Tdim + q0) * 128 + h * 2;
#pragma unroll
        for (int i = 0; i < 4; ++i) {
            const float rl = 1.0f / l[i];
            *reinterpret_cast<float2*>(Op + (size_t)i * 128) =
                make_float2(a0[i] * rl, a1[i] * rl);
        }
    }
}

// ---------------------------------------------------------------------------
// Kernel 3: output projection out = O @ Wo.T — same 1-wave structure.
// grid = (32, 8), block = 64.
// ---------------------------------------------------------------------------
__global__ __launch_bounds__(64) void out_proj(
    const float* __restrict__ Oin, const float* __restrict__ Wo,
    float* __restrict__ out)
{
    __shared__ __align__(16) float Ot[64][20];

    const int lane = threadIdx.x;
    const int row  = blockIdx.x * 64 + lane;
    const int jb   = blockIdx.y * 16;

    float4 xr[32];
    {
        const float4* xrow = reinterpret_cast<const float4*>(Oin + (size_t)row * 128);
#pragma unroll
        for (int k = 0; k < 32; ++k) xr[k] = xrow[k];
    }

    for (int cg = 0; cg < 4; ++cg) {
        const float4* w0 = reinterpret_cast<const float4*>(Wo + (size_t)(jb + cg * 4 + 0) * 128);
        const float4* w1 = reinterpret_cast<const float4*>(Wo + (size_t)(jb + cg * 4 + 1) * 128);
        const float4* w2 = reinterpret_cast<const float4*>(Wo + (size_t)(jb + cg * 4 + 2) * 128);
        const float4* w3 = reinterpret_cast<const float4*>(Wo + (size_t)(jb + cg * 4 + 3) * 128);
        float a0 = 0.f, a1 = 0.f, a2 = 0.f, a3 = 0.f;
#pragma unroll
        for (int k = 0; k < 32; ++k) {
            const float4 xv = xr[k];
            const float4 v0 = w0[k], v1 = w1[k], v2 = w2[k], v3 = w3[k];
            a0 = fmaf(xv.x, v0.x, fmaf(xv.y, v0.y, fmaf(xv.z, v0.z, fmaf(xv.w, v0.w, a0))));
            a1 = fmaf(xv.x, v1.x, fmaf(xv.y, v1.y, fmaf(xv.z, v1.z, fmaf(xv.w, v1.w, a1))));
            a2 = fmaf(xv.x, v2.x, fmaf(xv.y, v2.y, fmaf(xv.z, v2.z, fmaf(xv.w, v2.w, a2))));
            a3 = fmaf(xv.x, v3.x, fmaf(xv.y, v3.y, fmaf(xv.z, v3.z, fmaf(xv.w, v3.w, a3))));
        }
        Ot[lane][cg * 4 + 0] = a0;
        Ot[lane][cg * 4 + 1] = a1;
        Ot[lane][cg * 4 + 2] = a2;
        Ot[lane][cg * 4 + 3] = a3;
    }

    __syncthreads();
#pragma unroll
    for (int rep = 0; rep < 4; ++rep) {
        const int r = rep * 16 + (lane >> 2), c4 = lane & 3;
        const float4 v = *reinterpret_cast<const float4*>(&Ot[r][c4 * 4]);
        *reinterpret_cast<float4*>(out + (size_t)(blockIdx.x * 64 + r) * 128 + jb + c4 * 4) = v;
    }
}

extern "C" void kernel_launch(void* const* d_in, const int* in_sizes, int n_in,
                              void* d_out, int out_size, void* d_ws, size_t ws_size,
                              hipStream_t stream) {
    const float* x  = (const float*)d_in[0];
    const float* Wq = (const float*)d_in[1];
    const float* Wk = (const float*)d_in[2];
    const float* Wv = (const float*)d_in[3];
    const float* Wo = (const float*)d_in[4];
    float* out = (float*)d_out;

    // workspace: Q (B,T,D) 1MB | KV (B,H,T,4) 2MB | O (B,T,D) 1MB
    float* ws = (float*)d_ws;
    float* Q  = ws;
    float* KV = ws + 262144;
    float* O  = ws + 786432;

    qkv_proj<<<dim3(32, 8, 3), 64, 0, stream>>>(x, Wq, Wk, Wv, Q, KV);
    attn<<<dim3(8, 128), 256, 0, stream>>>(Q, (const float4*)KV, O);
    out_proj<<<dim3(32, 8), 64, 0, stream>>>(O, Wo, out);
}

// Round 5
// 95.344 us; speedup vs baseline: 1.6433x; 1.6433x over previous
//
#include <hip/hip_runtime.h>
#include <math.h>

#define Tdim 1024
#define Hh   64

#if __has_builtin(__builtin_amdgcn_exp2f)
#define EXP2(x) __builtin_amdgcn_exp2f(x)
#else
#define EXP2(x) exp2f(x)
#endif

// (1/(sqrt(2)*0.8)) * log2(e) — folded into Q so attention uses exp2 directly
__device__ __constant__ float kQScale = 0.8838834764831844f * 1.4426950408889634f;

// ---------------------------------------------------------------------------
// Kernel 1: fused QKV projection. y = x @ W.T for Wq,Wk,Wv (blockIdx.y picks W).
// grid = (128 row-groups of 16, 3), block = 256.
// Q written (B,T,D) pre-scaled by kQScale (coalesced stores);
// K,V packed into KV float4 (k0,k1,v0,v1) per (bh, t).
// ---------------------------------------------------------------------------
__global__ __launch_bounds__(256) void qkv_proj(
    const float* __restrict__ x, const float* __restrict__ Wq,
    const float* __restrict__ Wk, const float* __restrict__ Wv,
    float* __restrict__ Q, float* __restrict__ KV)
{
    __shared__ float xs[16][128];     // 8 KB
    __shared__ float Wch[128][36];    // 18 KB, 32-k chunk of W, pad->36

    const int tid  = threadIdx.x;
    const int row0 = blockIdx.x * 16;
    const int w    = blockIdx.y;      // 0=Q 1=K 2=V

    {
        const float4* xg = reinterpret_cast<const float4*>(x + (size_t)row0 * 128);
        reinterpret_cast<float4*>(&xs[0][0])[tid]       = xg[tid];
        reinterpret_cast<float4*>(&xs[0][0])[tid + 256] = xg[tid + 256];
    }

    const float* W = (w == 0) ? Wq : (w == 1) ? Wk : Wv;

    const int j0 = tid & 31;          // cols j0 + {0,32,64,96}
    const int r0 = (tid >> 5) << 1;   // rows r0, r0+1

    float acc[2][4];
#pragma unroll
    for (int r = 0; r < 2; ++r)
#pragma unroll
        for (int c = 0; c < 4; ++c) acc[r][c] = 0.f;

    for (int ch = 0; ch < 4; ++ch) {
        __syncthreads();
#pragma unroll
        for (int s = 0; s < 4; ++s) {
            const int idx  = tid + s * 256;   // 0..1023
            const int rowW = idx >> 3;
            const int c4   = idx & 7;
            *reinterpret_cast<float4*>(&Wch[rowW][c4 * 4]) =
                reinterpret_cast<const float4*>(W + (size_t)rowW * 128 + ch * 32)[c4];
        }
        __syncthreads();

#pragma unroll
        for (int c = 0; c < 8; ++c) {
            const float4 w0 = *reinterpret_cast<const float4*>(&Wch[j0      ][c * 4]);
            const float4 w1 = *reinterpret_cast<const float4*>(&Wch[j0 + 32 ][c * 4]);
            const float4 w2 = *reinterpret_cast<const float4*>(&Wch[j0 + 64 ][c * 4]);
            const float4 w3 = *reinterpret_cast<const float4*>(&Wch[j0 + 96 ][c * 4]);
#pragma unroll
            for (int r = 0; r < 2; ++r) {
                const float4 xv = *reinterpret_cast<const float4*>(&xs[r0 + r][ch * 32 + c * 4]);
                acc[r][0] = fmaf(xv.x, w0.x, fmaf(xv.y, w0.y, fmaf(xv.z, w0.z, fmaf(xv.w, w0.w, acc[r][0]))));
                acc[r][1] = fmaf(xv.x, w1.x, fmaf(xv.y, w1.y, fmaf(xv.z, w1.z, fmaf(xv.w, w1.w, acc[r][1]))));
                acc[r][2] = fmaf(xv.x, w2.x, fmaf(xv.y, w2.y, fmaf(xv.z, w2.z, fmaf(xv.w, w2.w, acc[r][2]))));
                acc[r][3] = fmaf(xv.x, w3.x, fmaf(xv.y, w3.y, fmaf(xv.z, w3.z, fmaf(xv.w, w3.w, acc[r][3]))));
            }
        }
    }

#pragma unroll
    for (int r = 0; r < 2; ++r) {
        const int row = row0 + r0 + r;
        const int bb  = row >> 10;
        const int t   = row & 1023;
#pragma unroll
        for (int jj = 0; jj < 4; ++jj) {
            const int j = j0 + jj * 32;
            const float v = acc[r][jj];
            if (w == 0) {
                Q[(size_t)row * 128 + j] = v * kQScale;
            } else {
                const int h  = j >> 1, dh = j & 1;
                const int bh = bb * Hh + h;
                KV[((size_t)bh * Tdim + t) * 4 + ((w == 1) ? dh : 2 + dh)] = v;
            }
        }
    }
}

// ---------------------------------------------------------------------------
// Kernel 2: causal attention, head_dim=2, single-pass no-max softmax in exp2
// domain. Balanced chunk pairing: block bx handles query chunks (c, 15-c);
// each thread owns 2 low + 2 high queries, 8 key sub-lanes -> every thread
// in every block performs exactly 240 query-key updates.
// grid = (8, B*H=128), block = 256.
// ---------------------------------------------------------------------------
__global__ __launch_bounds__(256) void attn(
    const float* __restrict__ Q, const float4* __restrict__ KV,
    float* __restrict__ O)
{
    __shared__ float4 KVs[Tdim];   // 16 KB
    const int tid   = threadIdx.x;
    const int c     = blockIdx.x;          // 0..7
    const int bh    = blockIdx.y;
    const int lowb  = c * 64;
    const int highb = (15 - c) * 64;
    const int nk    = highb + 64;          // keys needed: 0..nk-1

    const float4* KVg = KV + (size_t)bh * Tdim;
    for (int i = tid; i < nk; i += 256) KVs[i] = KVg[i];
    __syncthreads();

    const int sub = tid & 7;               // key sub-lane
    const int g   = tid >> 3;              // 0..31 query group
    const int lq  = lowb + g * 2;          // owns lq, lq+1
    const int hq  = highb + g * 2;         // owns hq, hq+1
    const int b   = bh >> 6, h = bh & 63;

    const float* Qb = Q + (size_t)b * (Tdim * 128) + h * 2;
    float2 q[4];
    q[0] = *reinterpret_cast<const float2*>(Qb + (size_t)(lq    ) * 128);
    q[1] = *reinterpret_cast<const float2*>(Qb + (size_t)(lq + 1) * 128);
    q[2] = *reinterpret_cast<const float2*>(Qb + (size_t)(hq    ) * 128);
    q[3] = *reinterpret_cast<const float2*>(Qb + (size_t)(hq + 1) * 128);

    float l[4]  = {0.f, 0.f, 0.f, 0.f};
    float a0[4] = {0.f, 0.f, 0.f, 0.f};
    float a1[4] = {0.f, 0.f, 0.f, 0.f};

    auto upd = [&](int i, const float4 kv) {
        const float p = EXP2(fmaf(q[i].x, kv.x, q[i].y * kv.y));
        l[i] += p;
        a0[i] = fmaf(p, kv.z, a0[i]);
        a1[i] = fmaf(p, kv.w, a1[i]);
    };

    // phase 1: keys [0, lq) at residue sub — all 4 queries
#pragma unroll 2
    for (int k = sub; k < lq; k += 8) {
        const float4 kv = KVs[k];
        upd(0, kv); upd(1, kv); upd(2, kv); upd(3, kv);
    }
    // low diagonal tail: key lq (queries lq, lq+1), key lq+1 (query lq+1)
    if (sub <= 1) {
        const float4 kv = KVs[lq + sub];
        if (sub == 0) upd(0, kv);
        upd(1, kv);
    }
    // phase 2: keys [lq.., hq) at residue sub — high queries only
    int k2 = (lq & ~7) + sub; if (k2 < lq) k2 += 8;
#pragma unroll 4
    for (int k = k2; k < hq; k += 8) {
        const float4 kv = KVs[k];
        upd(2, kv); upd(3, kv);
    }
    // high diagonal tail
    if (sub <= 1) {
        const float4 kv = KVs[hq + sub];
        if (sub == 0) upd(2, kv);
        upd(3, kv);
    }

    // reduce across 8 sub-lanes
#pragma unroll
    for (int i = 0; i < 4; ++i) {
        l[i]  += __shfl_xor(l[i], 1);  l[i]  += __shfl_xor(l[i], 2);  l[i]  += __shfl_xor(l[i], 4);
        a0[i] += __shfl_xor(a0[i], 1); a0[i] += __shfl_xor(a0[i], 2); a0[i] += __shfl_xor(a0[i], 4);
        a1[i] += __shfl_xor(a1[i], 1); a1[i] += __shfl_xor(a1[i], 2); a1[i] += __shfl_xor(a1[i], 4);
    }

    if (sub == 0) {
        float* Ob = O + (size_t)b * (Tdim * 128) + h * 2;
#pragma unroll
        for (int i = 0; i < 4; ++i) {
            const int row = (i < 2) ? (lq + i) : (hq + i - 2);
            const float rl = 1.0f / l[i];
            *reinterpret_cast<float2*>(Ob + (size_t)row * 128) =
                make_float2(a0[i] * rl, a1[i] * rl);
        }
    }
}

// ---------------------------------------------------------------------------
// Kernel 3: output projection out = O @ Wo.T (same structure as qkv_proj).
// grid = 128, block = 256.
// ---------------------------------------------------------------------------
__global__ __launch_bounds__(256) void out_proj(
    const float* __restrict__ Oin, const float* __restrict__ Wo,
    float* __restrict__ out)
{
    __shared__ float xs[16][128];
    __shared__ float Wch[128][36];

    const int tid  = threadIdx.x;
    const int row0 = blockIdx.x * 16;

    {
        const float4* xg = reinterpret_cast<const float4*>(Oin + (size_t)row0 * 128);
        reinterpret_cast<float4*>(&xs[0][0])[tid]       = xg[tid];
        reinterpret_cast<float4*>(&xs[0][0])[tid + 256] = xg[tid + 256];
    }

    const int j0 = tid & 31;
    const int r0 = (tid >> 5) << 1;

    float acc[2][4];
#pragma unroll
    for (int r = 0; r < 2; ++r)
#pragma unroll
        for (int c = 0; c < 4; ++c) acc[r][c] = 0.f;

    for (int ch = 0; ch < 4; ++ch) {
        __syncthreads();
#pragma unroll
        for (int s = 0; s < 4; ++s) {
            const int idx  = tid + s * 256;
            const int rowW = idx >> 3;
            const int c4   = idx & 7;
            *reinterpret_cast<float4*>(&Wch[rowW][c4 * 4]) =
                reinterpret_cast<const float4*>(Wo + (size_t)rowW * 128 + ch * 32)[c4];
        }
        __syncthreads();

#pragma unroll
        for (int c = 0; c < 8; ++c) {
            const float4 w0 = *reinterpret_cast<const float4*>(&Wch[j0      ][c * 4]);
            const float4 w1 = *reinterpret_cast<const float4*>(&Wch[j0 + 32 ][c * 4]);
            const float4 w2 = *reinterpret_cast<const float4*>(&Wch[j0 + 64 ][c * 4]);
            const float4 w3 = *reinterpret_cast<const float4*>(&Wch[j0 + 96 ][c * 4]);
#pragma unroll
            for (int r = 0; r < 2; ++r) {
                const float4 xv = *reinterpret_cast<const float4*>(&xs[r0 + r][ch * 32 + c * 4]);
                acc[r][0] = fmaf(xv.x, w0.x, fmaf(xv.y, w0.y, fmaf(xv.z, w0.z, fmaf(xv.w, w0.w, acc[r][0]))));
                acc[r][1] = fmaf(xv.x, w1.x, fmaf(xv.y, w1.y, fmaf(xv.z, w1.z, fmaf(xv.w, w1.w, acc[r][1]))));
                acc[r][2] = fmaf(xv.x, w2.x, fmaf(xv.y, w2.y, fmaf(xv.z, w2.z, fmaf(xv.w, w2.w, acc[r][2]))));
                acc[r][3] = fmaf(xv.x, w3.x, fmaf(xv.y, w3.y, fmaf(xv.z, w3.z, fmaf(xv.w, w3.w, acc[r][3]))));
            }
        }
    }

#pragma unroll
    for (int r = 0; r < 2; ++r) {
        const int row = row0 + r0 + r;
#pragma unroll
        for (int jj = 0; jj < 4; ++jj) {
            const int j = j0 + jj * 32;
            out[(size_t)row * 128 + j] = acc[r][jj];
        }
    }
}

extern "C" void kernel_launch(void* const* d_in, const int* in_sizes, int n_in,
                              void* d_out, int out_size, void* d_ws, size_t ws_size,
                              hipStream_t stream) {
    const float* x  = (const float*)d_in[0];
    const float* Wq = (const float*)d_in[1];
    const float* Wk = (const float*)d_in[2];
    const float* Wv = (const float*)d_in[3];
    const float* Wo = (const float*)d_in[4];
    float* out = (float*)d_out;

    // workspace: Q (B,T,D) 1MB | KV (B,H,T,4) 2MB | O (B,T,D) 1MB
    float* ws = (float*)d_ws;
    float* Q  = ws;
    float* KV = ws + 262144;
    float* O  = ws + 786432;

    qkv_proj<<<dim3(128, 3), 256, 0, stream>>>(x, Wq, Wk, Wv, Q, KV);
    attn<<<dim3(8, 128), 256, 0, stream>>>(Q, (const float4*)KV, O);
    out_proj<<<128, 256, 0, stream>>>(O, Wo, out);
}